// Round 3
// baseline (146.505 us; speedup 1.0000x reference)
//
#include <hip/hip_runtime.h>

#define B_ 4
#define S_ 512
#define T_ 512
#define D_ 256
#define NSRC (B_ * S_)            // 2048 source rows
#define K2F 2.8853900817779268f   // 2*log2(e): exp2(x*K2F) = e^(2x)

typedef __attribute__((ext_vector_type(8))) short short8;   // 8 bf16
typedef __attribute__((ext_vector_type(4))) float f32x4;
typedef __attribute__((ext_vector_type(2))) float f32x2;

__device__ __forceinline__ unsigned short f2bf(float f) {
    union { float f; unsigned u; } v; v.f = f;
    unsigned r = v.u + 0x7FFF + ((v.u >> 16) & 1);   // RNE
    return (unsigned short)(r >> 16);
}

// ---------------------------------------------------------------------------
// K1: prep. blocks 0..31: W -> WT bf16 via LDS 64x64 tile transpose.
//     blocks 32..543: prob = softmax(target @ W_prob + b_prob).
// ---------------------------------------------------------------------------
__global__ __launch_bounds__(256) void prep_kernel(
    const float* __restrict__ tgt,
    const float* __restrict__ Wsrc, const float* __restrict__ Wtgt,
    const float* __restrict__ Wp, const float* __restrict__ bp,
    unsigned short* __restrict__ wtb, float* __restrict__ out)
{
    __shared__ float tl[64 * 65];
    const int blk = blockIdx.x, tid = threadIdx.x;

    if (blk < 32) {
        int wb = blk;
        int e = wb >> 4, ti = wb & 15, tr = ti >> 2, tc = ti & 3;
        int r0 = tr * 64, c0 = tc * 64;
        const float* W = e ? Wtgt : Wsrc;
        #pragma unroll
        for (int it = 0; it < 4; it++) {
            int rr = (tid >> 4) + it * 16;
            int cc = (tid & 15) * 4;
            float4 v = *(const float4*)&W[(r0 + rr) * D_ + c0 + cc];
            tl[(cc + 0) * 65 + rr] = v.x;
            tl[(cc + 1) * 65 + rr] = v.y;
            tl[(cc + 2) * 65 + rr] = v.z;
            tl[(cc + 3) * 65 + rr] = v.w;
        }
        __syncthreads();
        #pragma unroll
        for (int it = 0; it < 2; it++) {
            int jj = (tid >> 3) + it * 32;
            int kk = (tid & 7) * 8;
            ushort4 lo, hi;
            lo.x = f2bf(tl[jj * 65 + kk + 0]); lo.y = f2bf(tl[jj * 65 + kk + 1]);
            lo.z = f2bf(tl[jj * 65 + kk + 2]); lo.w = f2bf(tl[jj * 65 + kk + 3]);
            hi.x = f2bf(tl[jj * 65 + kk + 4]); hi.y = f2bf(tl[jj * 65 + kk + 5]);
            hi.z = f2bf(tl[jj * 65 + kk + 6]); hi.w = f2bf(tl[jj * 65 + kk + 7]);
            int idx = (e * 256 + c0 + jj) * D_ + r0 + kk;
            *(ushort4*)&wtb[idx] = lo;
            *(ushort4*)&wtb[idx + 4] = hi;
        }
    } else {
        int row  = (blk - 32) * 4 + (tid >> 6);
        int lane = tid & 63;
        float p0 = 0.f, p1 = 0.f;
        #pragma unroll
        for (int i = 0; i < 4; i++) {
            int d = lane + i * 64;
            float v = tgt[row * D_ + d];
            float2 w = *(const float2*)&Wp[d * 2];
            p0 = fmaf(v, w.x, p0);
            p1 = fmaf(v, w.y, p1);
        }
        #pragma unroll
        for (int off = 32; off > 0; off >>= 1) {
            p0 += __shfl_down(p0, off, 64);
            p1 += __shfl_down(p1, off, 64);
        }
        if (lane == 0) {
            const float L2E = 1.4426950408889634f;
            float l0 = p0 + bp[0], l1 = p1 + bp[1];
            float e10 = __builtin_amdgcn_exp2f((l1 - l0) * L2E);
            float e01 = __builtin_amdgcn_exp2f((l0 - l1) * L2E);
            out[B_ * T_ * S_ + row * 2 + 0] = __builtin_amdgcn_rcpf(1.f + e10);
            out[B_ * T_ * S_ + row * 2 + 1] = __builtin_amdgcn_rcpf(1.f + e01);
        }
    }
}

// ---------------------------------------------------------------------------
// K2: mega v12 — 2 blocks/CU, rowgroup-split producers (no break-in-unroll).
// Tile 64s x 32t, block = 512 threads = 8 waves (4 producer + 4 consumer),
// grid (8,16,4) = 512 blocks = exactly 2 blocks/CU (LDS 68KB x2 = 136KB,
// VGPR cap 128 at 4 waves/SIMD).
// Producer roles (ALL waves run the identical all-4-cg phase loop):
//   w0: s-mat rows 0..31 (rb=0, 2 rowgroups)
//   w1: s-mat rows 32..63 (rb=2, 2 rowgroups)
//   w2: t-mat rows 0..15  (rb=0, 1 rowgroup)
//   w3: t-mat rows 16..31 (rb=1, 1 rowgroup)
// The only wave-divergent construct is a uniform `if (mat==0)` guarding the
// second rowgroup — structurally minimal delta from the verified R1 kernel.
// Consumers: 4 waves, each thread 2t x 4s, 8-term rcp folding (unchanged).
// genP = C0 - 2 * sum_d w_d / (1 + ys*yt),  C0 = sum w + b_res.
// ---------------------------------------------------------------------------
#define LSTR 68
__global__ __launch_bounds__(512, 4) void mega_kernel(
    const float* __restrict__ src, const float* __restrict__ tgt,
    const unsigned short* __restrict__ wtb,
    const float* __restrict__ bsrc, const float* __restrict__ btgt,
    const float* __restrict__ Wres, const float* __restrict__ bres,
    float* __restrict__ out)
{
    __shared__ float ls[2][64 * LSTR];   // [buf][d][s]   s = 0..63
    __shared__ float lt[2][64 * LSTR];   // [buf][d][t]   t = 0..31 (rows 32+ unused)
    __shared__ float c0s;

    const int tid = threadIdx.x;
    const int lane = tid & 63, w = tid >> 6;
    const int s0 = blockIdx.x * 64;
    const int t0 = blockIdx.y * 32;
    const int b  = blockIdx.z;

    if (w == 0) {
        float s = Wres[lane] + Wres[lane + 64] + Wres[lane + 128] + Wres[lane + 192];
        #pragma unroll
        for (int off = 32; off > 0; off >>= 1) s += __shfl_xor(s, off, 64);
        if (lane == 0) c0s = s + bres[0];
    }

    const bool producer = (w < 4);
    const int n = lane & 15, quad = lane >> 4;

    // ---- producer state ----
    const int mat = (w >> 1) & 1;                // 0 = s-mat (w0,w1), 1 = t-mat (w2,w3)
    const int rb  = mat ? (w & 1) : 2 * (w & 1); // w0:0 w1:2 w2:0 w3:1
    const float* bias = mat ? btgt : bsrc;
    const unsigned short* wtbase = wtb + mat * 256 * D_;

    short8 af[2][8];
    if (producer) {
        const float* xb = mat ? &tgt[(b * T_ + t0) * D_] : &src[(b * S_ + s0) * D_];
        #pragma unroll
        for (int ks = 0; ks < 8; ks++) {
            const float* p = &xb[(rb * 16 + n) * D_ + ks * 32 + quad * 8];
            float4 u0 = *(const float4*)p;
            float4 u1 = *(const float4*)(p + 4);
            short8 v;
            v[0] = (short)f2bf(u0.x); v[1] = (short)f2bf(u0.y);
            v[2] = (short)f2bf(u0.z); v[3] = (short)f2bf(u0.w);
            v[4] = (short)f2bf(u1.x); v[5] = (short)f2bf(u1.y);
            v[6] = (short)f2bf(u1.z); v[7] = (short)f2bf(u1.w);
            af[0][ks] = v;
        }
        if (mat == 0) {
            #pragma unroll
            for (int ks = 0; ks < 8; ks++) {
                const float* p = &xb[((rb + 1) * 16 + n) * D_ + ks * 32 + quad * 8];
                float4 u0 = *(const float4*)p;
                float4 u1 = *(const float4*)(p + 4);
                short8 v;
                v[0] = (short)f2bf(u0.x); v[1] = (short)f2bf(u0.y);
                v[2] = (short)f2bf(u0.z); v[3] = (short)f2bf(u0.w);
                v[4] = (short)f2bf(u1.x); v[5] = (short)f2bf(u1.y);
                v[6] = (short)f2bf(u1.z); v[7] = (short)f2bf(u1.w);
                af[1][ks] = v;
            }
        }
    }

    auto phaseA = [&](int c, int bi) {
        float* lx = (mat ? lt[bi] : ls[bi]);
        #pragma unroll
        for (int cg = 0; cg < 4; cg++) {
            const int gcol = c * 4 + cg;
            const unsigned short* bptr = &wtbase[(gcol * 16 + n) * D_ + quad * 8];
            short8 bf[8];
            #pragma unroll
            for (int ks = 0; ks < 8; ks++) bf[ks] = *(const short8*)&bptr[ks * 32];
            const int dloc = cg * 16 + n;
            const float bv = bias[gcol * 16 + n];
            {   // rowgroup 0 (all producer waves)
                f32x4 a4 = {0.f, 0.f, 0.f, 0.f};
                #pragma unroll
                for (int ks = 0; ks < 8; ks++)
                    a4 = __builtin_amdgcn_mfma_f32_16x16x32_bf16(af[0][ks], bf[ks], a4, 0, 0, 0);
                float4 o;
                o.x = __builtin_amdgcn_exp2f((a4[0] + bv) * K2F);
                o.y = __builtin_amdgcn_exp2f((a4[1] + bv) * K2F);
                o.z = __builtin_amdgcn_exp2f((a4[2] + bv) * K2F);
                o.w = __builtin_amdgcn_exp2f((a4[3] + bv) * K2F);
                *(float4*)&lx[dloc * LSTR + rb * 16 + quad * 4] = o;
            }
            if (mat == 0) {   // rowgroup 1 (s-waves only; wave-uniform)
                f32x4 a4 = {0.f, 0.f, 0.f, 0.f};
                #pragma unroll
                for (int ks = 0; ks < 8; ks++)
                    a4 = __builtin_amdgcn_mfma_f32_16x16x32_bf16(af[1][ks], bf[ks], a4, 0, 0, 0);
                float4 o;
                o.x = __builtin_amdgcn_exp2f((a4[0] + bv) * K2F);
                o.y = __builtin_amdgcn_exp2f((a4[1] + bv) * K2F);
                o.z = __builtin_amdgcn_exp2f((a4[2] + bv) * K2F);
                o.w = __builtin_amdgcn_exp2f((a4[3] + bv) * K2F);
                *(float4*)&lx[dloc * LSTR + (rb + 1) * 16 + quad * 4] = o;
            }
        }
    };

    // ---- consumer state ----
    const int cl = tid - 256;            // 0..255
    const int m = cl & 15;               // s = s0 + 4m..4m+3
    const int g = cl >> 4;               // t = t0 + 2g, 2g+1   (0..15)
    f32x2 acc[2][2];                     // [t-idx i][s-pair jp]
    #pragma unroll
    for (int i = 0; i < 2; i++) {
        acc[i][0] = (f32x2){0.f, 0.f};
        acc[i][1] = (f32x2){0.f, 0.f};
    }

    if (producer) phaseA(0, 0);
    __syncthreads();

    for (int c = 0; c < 4; c++) {
        const int bi = c & 1;
        if (producer) {
            if (c < 3) phaseA(c + 1, bi ^ 1);
        } else {
            const float* lsb = ls[bi];
            const float* ltb = lt[bi];
            const float* wp = &Wres[c * 64];
            const f32x2 one2 = {1.f, 1.f};
            #pragma unroll 2
            for (int kq = 0; kq < 8; kq++) {
                const int d0 = 8 * kq;
                f32x2 ap[8][2];          // [k][s-pair]
                float cc[8][2];          // [k][t-idx]
                f32x2 wv[8];
                #pragma unroll
                for (int k = 0; k < 8; k++) {
                    float4 a4 = *(const float4*)&lsb[(d0 + k) * LSTR + 4 * m];
                    float2 c2 = *(const float2*)&ltb[(d0 + k) * LSTR + 2 * g];
                    ap[k][0] = (f32x2){a4.x, a4.y};
                    ap[k][1] = (f32x2){a4.z, a4.w};
                    cc[k][0] = c2.x; cc[k][1] = c2.y;
                    const float wk = wp[d0 + k];     // uniform s_load
                    wv[k] = (f32x2){wk, wk};
                }
                #pragma unroll
                for (int i = 0; i < 2; i++) {
                    #pragma unroll
                    for (int jp = 0; jp < 2; jp++) {
                        f32x2 dd[8];
                        #pragma unroll
                        for (int k = 0; k < 8; k++) {
                            const f32x2 cs = {cc[k][i], cc[k][i]};
                            dd[k] = ap[k][jp] * cs + one2;   // 1 + ys*yt
                        }
                        f32x2 p01 = dd[0] * dd[1];
                        f32x2 p23 = dd[2] * dd[3];
                        f32x2 p45 = dd[4] * dd[5];
                        f32x2 p67 = dd[6] * dd[7];
                        f32x2 q03 = p01 * p23;
                        f32x2 q47 = p45 * p67;
                        f32x2 den = q03 * q47;
                        f32x2 u01 = dd[1] * wv[0]; u01 = dd[0] * wv[1] + u01;
                        f32x2 u23 = dd[3] * wv[2]; u23 = dd[2] * wv[3] + u23;
                        f32x2 u45 = dd[5] * wv[4]; u45 = dd[4] * wv[5] + u45;
                        f32x2 u67 = dd[7] * wv[6]; u67 = dd[6] * wv[7] + u67;
                        f32x2 n03 = u01 * p23; n03 = u23 * p01 + n03;
                        f32x2 n47 = u45 * p67; n47 = u67 * p45 + n47;
                        f32x2 num = n03 * q47; num = n47 * q03 + num;
                        f32x2 r;
                        r.x = __builtin_amdgcn_rcpf(den.x);
                        r.y = __builtin_amdgcn_rcpf(den.y);
                        acc[i][jp] = num * r + acc[i][jp];
                    }
                }
            }
        }
        __syncthreads();
    }

    if (!producer) {
        const float C0 = c0s;
        #pragma unroll
        for (int i = 0; i < 2; i++) {
            float4 o;
            o.x = C0 - 2.f * acc[i][0].x;
            o.y = C0 - 2.f * acc[i][0].y;
            o.z = C0 - 2.f * acc[i][1].x;
            o.w = C0 - 2.f * acc[i][1].y;
            *(float4*)&out[(b * T_ + t0 + 2 * g + i) * S_ + s0 + 4 * m] = o;
        }
    }
}

extern "C" void kernel_launch(void* const* d_in, const int* in_sizes, int n_in,
                              void* d_out, int out_size, void* d_ws, size_t ws_size,
                              hipStream_t stream) {
    const float* source = (const float*)d_in[0];
    const float* target = (const float*)d_in[1];
    const float* W_src  = (const float*)d_in[2];
    const float* b_src  = (const float*)d_in[3];
    const float* W_tgt  = (const float*)d_in[4];
    const float* b_tgt  = (const float*)d_in[5];
    const float* W_res  = (const float*)d_in[6];
    const float* b_res  = (const float*)d_in[7];
    const float* W_prob = (const float*)d_in[8];
    const float* b_prob = (const float*)d_in[9];
    float* out = (float*)d_out;

    unsigned short* wtb = (unsigned short*)d_ws;    // 2*256*256 bf16 = 256 KB

    prep_kernel<<<544, 256, 0, stream>>>(target, W_src, W_tgt,
                                         W_prob, b_prob, wtb, out);
    mega_kernel<<<dim3(8, 16, 4), 512, 0, stream>>>(source, target, wtb,
                                                    b_src, b_tgt,
                                                    W_res, b_res, out);
}

// Round 4
// 145.631 us; speedup vs baseline: 1.0060x; 1.0060x over previous
//
#include <hip/hip_runtime.h>

#define B_ 4
#define S_ 512
#define T_ 512
#define D_ 256
#define NSRC (B_ * S_)            // 2048 source rows
#define K2F 2.8853900817779268f   // 2*log2(e): exp2(x*K2F) = e^(2x)

typedef __attribute__((ext_vector_type(8))) short short8;   // 8 bf16
typedef __attribute__((ext_vector_type(4))) float f32x4;
typedef __attribute__((ext_vector_type(2))) float f32x2;

__device__ __forceinline__ unsigned short f2bf(float f) {
    union { float f; unsigned u; } v; v.f = f;
    unsigned r = v.u + 0x7FFF + ((v.u >> 16) & 1);   // RNE
    return (unsigned short)(r >> 16);
}

// ---------------------------------------------------------------------------
// K1: prep. blocks 0..31: W -> WT bf16 via LDS 64x64 tile transpose.
//     blocks 32..543: prob = softmax(target @ W_prob + b_prob).
// ---------------------------------------------------------------------------
__global__ __launch_bounds__(256) void prep_kernel(
    const float* __restrict__ tgt,
    const float* __restrict__ Wsrc, const float* __restrict__ Wtgt,
    const float* __restrict__ Wp, const float* __restrict__ bp,
    unsigned short* __restrict__ wtb, float* __restrict__ out)
{
    __shared__ float tl[64 * 65];
    const int blk = blockIdx.x, tid = threadIdx.x;

    if (blk < 32) {
        int wb = blk;
        int e = wb >> 4, ti = wb & 15, tr = ti >> 2, tc = ti & 3;
        int r0 = tr * 64, c0 = tc * 64;
        const float* W = e ? Wtgt : Wsrc;
        #pragma unroll
        for (int it = 0; it < 4; it++) {
            int rr = (tid >> 4) + it * 16;
            int cc = (tid & 15) * 4;
            float4 v = *(const float4*)&W[(r0 + rr) * D_ + c0 + cc];
            tl[(cc + 0) * 65 + rr] = v.x;
            tl[(cc + 1) * 65 + rr] = v.y;
            tl[(cc + 2) * 65 + rr] = v.z;
            tl[(cc + 3) * 65 + rr] = v.w;
        }
        __syncthreads();
        #pragma unroll
        for (int it = 0; it < 2; it++) {
            int jj = (tid >> 3) + it * 32;
            int kk = (tid & 7) * 8;
            ushort4 lo, hi;
            lo.x = f2bf(tl[jj * 65 + kk + 0]); lo.y = f2bf(tl[jj * 65 + kk + 1]);
            lo.z = f2bf(tl[jj * 65 + kk + 2]); lo.w = f2bf(tl[jj * 65 + kk + 3]);
            hi.x = f2bf(tl[jj * 65 + kk + 4]); hi.y = f2bf(tl[jj * 65 + kk + 5]);
            hi.z = f2bf(tl[jj * 65 + kk + 6]); hi.w = f2bf(tl[jj * 65 + kk + 7]);
            int idx = (e * 256 + c0 + jj) * D_ + r0 + kk;
            *(ushort4*)&wtb[idx] = lo;
            *(ushort4*)&wtb[idx + 4] = hi;
        }
    } else {
        int row  = (blk - 32) * 4 + (tid >> 6);
        int lane = tid & 63;
        float p0 = 0.f, p1 = 0.f;
        #pragma unroll
        for (int i = 0; i < 4; i++) {
            int d = lane + i * 64;
            float v = tgt[row * D_ + d];
            float2 w = *(const float2*)&Wp[d * 2];
            p0 = fmaf(v, w.x, p0);
            p1 = fmaf(v, w.y, p1);
        }
        #pragma unroll
        for (int off = 32; off > 0; off >>= 1) {
            p0 += __shfl_down(p0, off, 64);
            p1 += __shfl_down(p1, off, 64);
        }
        if (lane == 0) {
            const float L2E = 1.4426950408889634f;
            float l0 = p0 + bp[0], l1 = p1 + bp[1];
            float e10 = __builtin_amdgcn_exp2f((l1 - l0) * L2E);
            float e01 = __builtin_amdgcn_exp2f((l0 - l1) * L2E);
            out[B_ * T_ * S_ + row * 2 + 0] = __builtin_amdgcn_rcpf(1.f + e10);
            out[B_ * T_ * S_ + row * 2 + 1] = __builtin_amdgcn_rcpf(1.f + e01);
        }
    }
}

// ---------------------------------------------------------------------------
// K2: mega v13 — v12 structure with the spill fixed.
// v12 post-mortem: __launch_bounds__(512,4) sets waves-per-eu MIN only; the
// allocator targeted 8 waves/EU (64-VGPR bin) and spilled ~20 VGPRs ->
// WRITE_SIZE 63MB of scratch, mega 78us. Fix: pin waves_per_eu(4,4) ->
// 128-VGPR budget, natural ~84-90 pressure fits, no spill; occupancy is then
// grid/LDS-limited at exactly 2 blocks/CU (16 waves = 4/SIMD).
// Tile 64s x 32t, block = 512 threads = 8 waves (4 producer + 4 consumer),
// grid (8,16,4) = 512 blocks = 2/CU (LDS 70KB x2 = 140KB <= 160KB).
// Producer roles (all waves run the identical all-4-cg phase loop):
//   w0: s-mat rows 0..31 (rb=0) | w1: s-mat rows 32..63 (rb=2)
//   w2: t-mat rows 0..15  (rb=0) | w3: t-mat rows 16..31 (rb=1)
// Consumers: 4 waves, each thread 2t x 4s, 8-term rcp folding.
// genP = C0 - 2 * sum_d w_d / (1 + ys*yt),  C0 = sum w + b_res.
// ---------------------------------------------------------------------------
#define LSTR 68
__global__ __launch_bounds__(512)
__attribute__((amdgpu_waves_per_eu(4, 4)))
void mega_kernel(
    const float* __restrict__ src, const float* __restrict__ tgt,
    const unsigned short* __restrict__ wtb,
    const float* __restrict__ bsrc, const float* __restrict__ btgt,
    const float* __restrict__ Wres, const float* __restrict__ bres,
    float* __restrict__ out)
{
    __shared__ float ls[2][64 * LSTR];   // [buf][d][s]   s = 0..63
    __shared__ float lt[2][64 * LSTR];   // [buf][d][t]   t = 0..31 (rows 32+ unused)
    __shared__ float c0s;

    const int tid = threadIdx.x;
    const int lane = tid & 63, w = tid >> 6;
    const int s0 = blockIdx.x * 64;
    const int t0 = blockIdx.y * 32;
    const int b  = blockIdx.z;

    if (w == 0) {
        float s = Wres[lane] + Wres[lane + 64] + Wres[lane + 128] + Wres[lane + 192];
        #pragma unroll
        for (int off = 32; off > 0; off >>= 1) s += __shfl_xor(s, off, 64);
        if (lane == 0) c0s = s + bres[0];
    }

    const bool producer = (w < 4);
    const int n = lane & 15, quad = lane >> 4;

    // ---- producer state ----
    const int mat = (w >> 1) & 1;                // 0 = s-mat (w0,w1), 1 = t-mat (w2,w3)
    const int rb  = mat ? (w & 1) : 2 * (w & 1); // w0:0 w1:2 w2:0 w3:1
    const float* bias = mat ? btgt : bsrc;
    const unsigned short* wtbase = wtb + mat * 256 * D_;

    short8 af[2][8];
    if (producer) {
        const float* xb = mat ? &tgt[(b * T_ + t0) * D_] : &src[(b * S_ + s0) * D_];
        #pragma unroll
        for (int ks = 0; ks < 8; ks++) {
            const float* p = &xb[(rb * 16 + n) * D_ + ks * 32 + quad * 8];
            float4 u0 = *(const float4*)p;
            float4 u1 = *(const float4*)(p + 4);
            short8 v;
            v[0] = (short)f2bf(u0.x); v[1] = (short)f2bf(u0.y);
            v[2] = (short)f2bf(u0.z); v[3] = (short)f2bf(u0.w);
            v[4] = (short)f2bf(u1.x); v[5] = (short)f2bf(u1.y);
            v[6] = (short)f2bf(u1.z); v[7] = (short)f2bf(u1.w);
            af[0][ks] = v;
        }
        if (mat == 0) {
            #pragma unroll
            for (int ks = 0; ks < 8; ks++) {
                const float* p = &xb[((rb + 1) * 16 + n) * D_ + ks * 32 + quad * 8];
                float4 u0 = *(const float4*)p;
                float4 u1 = *(const float4*)(p + 4);
                short8 v;
                v[0] = (short)f2bf(u0.x); v[1] = (short)f2bf(u0.y);
                v[2] = (short)f2bf(u0.z); v[3] = (short)f2bf(u0.w);
                v[4] = (short)f2bf(u1.x); v[5] = (short)f2bf(u1.y);
                v[6] = (short)f2bf(u1.z); v[7] = (short)f2bf(u1.w);
                af[1][ks] = v;
            }
        }
    }

    auto phaseA = [&](int c, int bi) {
        float* lx = (mat ? lt[bi] : ls[bi]);
        #pragma unroll
        for (int cg = 0; cg < 4; cg++) {
            const int gcol = c * 4 + cg;
            const unsigned short* bptr = &wtbase[(gcol * 16 + n) * D_ + quad * 8];
            short8 bf[8];
            #pragma unroll
            for (int ks = 0; ks < 8; ks++) bf[ks] = *(const short8*)&bptr[ks * 32];
            const int dloc = cg * 16 + n;
            const float bv = bias[gcol * 16 + n];
            {   // rowgroup 0 (all producer waves)
                f32x4 a4 = {0.f, 0.f, 0.f, 0.f};
                #pragma unroll
                for (int ks = 0; ks < 8; ks++)
                    a4 = __builtin_amdgcn_mfma_f32_16x16x32_bf16(af[0][ks], bf[ks], a4, 0, 0, 0);
                float4 o;
                o.x = __builtin_amdgcn_exp2f((a4[0] + bv) * K2F);
                o.y = __builtin_amdgcn_exp2f((a4[1] + bv) * K2F);
                o.z = __builtin_amdgcn_exp2f((a4[2] + bv) * K2F);
                o.w = __builtin_amdgcn_exp2f((a4[3] + bv) * K2F);
                *(float4*)&lx[dloc * LSTR + rb * 16 + quad * 4] = o;
            }
            if (mat == 0) {   // rowgroup 1 (s-waves only; wave-uniform)
                f32x4 a4 = {0.f, 0.f, 0.f, 0.f};
                #pragma unroll
                for (int ks = 0; ks < 8; ks++)
                    a4 = __builtin_amdgcn_mfma_f32_16x16x32_bf16(af[1][ks], bf[ks], a4, 0, 0, 0);
                float4 o;
                o.x = __builtin_amdgcn_exp2f((a4[0] + bv) * K2F);
                o.y = __builtin_amdgcn_exp2f((a4[1] + bv) * K2F);
                o.z = __builtin_amdgcn_exp2f((a4[2] + bv) * K2F);
                o.w = __builtin_amdgcn_exp2f((a4[3] + bv) * K2F);
                *(float4*)&lx[dloc * LSTR + (rb + 1) * 16 + quad * 4] = o;
            }
        }
    };

    // ---- consumer state ----
    const int cl = tid - 256;            // 0..255
    const int m = cl & 15;               // s = s0 + 4m..4m+3
    const int g = cl >> 4;               // t = t0 + 2g, 2g+1   (0..15)
    f32x2 acc[2][2];                     // [t-idx i][s-pair jp]
    #pragma unroll
    for (int i = 0; i < 2; i++) {
        acc[i][0] = (f32x2){0.f, 0.f};
        acc[i][1] = (f32x2){0.f, 0.f};
    }

    if (producer) phaseA(0, 0);
    __syncthreads();

    for (int c = 0; c < 4; c++) {
        const int bi = c & 1;
        if (producer) {
            if (c < 3) phaseA(c + 1, bi ^ 1);
        } else {
            const float* lsb = ls[bi];
            const float* ltb = lt[bi];
            const float* wp = &Wres[c * 64];
            const f32x2 one2 = {1.f, 1.f};
            #pragma unroll 2
            for (int kq = 0; kq < 8; kq++) {
                const int d0 = 8 * kq;
                f32x2 ap[8][2];          // [k][s-pair]
                float cc[8][2];          // [k][t-idx]
                f32x2 wv[8];
                #pragma unroll
                for (int k = 0; k < 8; k++) {
                    float4 a4 = *(const float4*)&lsb[(d0 + k) * LSTR + 4 * m];
                    float2 c2 = *(const float2*)&ltb[(d0 + k) * LSTR + 2 * g];
                    ap[k][0] = (f32x2){a4.x, a4.y};
                    ap[k][1] = (f32x2){a4.z, a4.w};
                    cc[k][0] = c2.x; cc[k][1] = c2.y;
                    const float wk = wp[d0 + k];     // uniform s_load
                    wv[k] = (f32x2){wk, wk};
                }
                #pragma unroll
                for (int i = 0; i < 2; i++) {
                    #pragma unroll
                    for (int jp = 0; jp < 2; jp++) {
                        f32x2 dd[8];
                        #pragma unroll
                        for (int k = 0; k < 8; k++) {
                            const f32x2 cs = {cc[k][i], cc[k][i]};
                            dd[k] = ap[k][jp] * cs + one2;   // 1 + ys*yt
                        }
                        f32x2 p01 = dd[0] * dd[1];
                        f32x2 p23 = dd[2] * dd[3];
                        f32x2 p45 = dd[4] * dd[5];
                        f32x2 p67 = dd[6] * dd[7];
                        f32x2 q03 = p01 * p23;
                        f32x2 q47 = p45 * p67;
                        f32x2 den = q03 * q47;
                        f32x2 u01 = dd[1] * wv[0]; u01 = dd[0] * wv[1] + u01;
                        f32x2 u23 = dd[3] * wv[2]; u23 = dd[2] * wv[3] + u23;
                        f32x2 u45 = dd[5] * wv[4]; u45 = dd[4] * wv[5] + u45;
                        f32x2 u67 = dd[7] * wv[6]; u67 = dd[6] * wv[7] + u67;
                        f32x2 n03 = u01 * p23; n03 = u23 * p01 + n03;
                        f32x2 n47 = u45 * p67; n47 = u67 * p45 + n47;
                        f32x2 num = n03 * q47; num = n47 * q03 + num;
                        f32x2 r;
                        r.x = __builtin_amdgcn_rcpf(den.x);
                        r.y = __builtin_amdgcn_rcpf(den.y);
                        acc[i][jp] = num * r + acc[i][jp];
                    }
                }
            }
        }
        __syncthreads();
    }

    if (!producer) {
        const float C0 = c0s;
        #pragma unroll
        for (int i = 0; i < 2; i++) {
            float4 o;
            o.x = C0 - 2.f * acc[i][0].x;
            o.y = C0 - 2.f * acc[i][0].y;
            o.z = C0 - 2.f * acc[i][1].x;
            o.w = C0 - 2.f * acc[i][1].y;
            *(float4*)&out[(b * T_ + t0 + 2 * g + i) * S_ + s0 + 4 * m] = o;
        }
    }
}

extern "C" void kernel_launch(void* const* d_in, const int* in_sizes, int n_in,
                              void* d_out, int out_size, void* d_ws, size_t ws_size,
                              hipStream_t stream) {
    const float* source = (const float*)d_in[0];
    const float* target = (const float*)d_in[1];
    const float* W_src  = (const float*)d_in[2];
    const float* b_src  = (const float*)d_in[3];
    const float* W_tgt  = (const float*)d_in[4];
    const float* b_tgt  = (const float*)d_in[5];
    const float* W_res  = (const float*)d_in[6];
    const float* b_res  = (const float*)d_in[7];
    const float* W_prob = (const float*)d_in[8];
    const float* b_prob = (const float*)d_in[9];
    float* out = (float*)d_out;

    unsigned short* wtb = (unsigned short*)d_ws;    // 2*256*256 bf16 = 256 KB

    prep_kernel<<<544, 256, 0, stream>>>(target, W_src, W_tgt,
                                         W_prob, b_prob, wtb, out);
    mega_kernel<<<dim3(8, 16, 4), 512, 0, stream>>>(source, target, wtb,
                                                    b_src, b_tgt,
                                                    W_res, b_res, out);
}

// Round 5
// 107.122 us; speedup vs baseline: 1.3676x; 1.3595x over previous
//
#include <hip/hip_runtime.h>

#define B_ 4
#define S_ 512
#define T_ 512
#define D_ 256
#define NSRC (B_ * S_)            // 2048 source rows
#define NROW 4096                 // src rows + tgt rows
#define K2F 2.8853900817779268f   // 2*log2(e): exp2(x*K2F) = e^(2x)

typedef __attribute__((ext_vector_type(8))) short short8;   // 8 bf16
typedef __attribute__((ext_vector_type(4))) float f32x4;
typedef __attribute__((ext_vector_type(2))) float f32x2;

__device__ __forceinline__ unsigned short f2bf(float f) {
    union { float f; unsigned u; } v; v.f = f;
    unsigned r = v.u + 0x7FFF + ((v.u >> 16) & 1);   // RNE
    return (unsigned short)(r >> 16);
}

// ---------------------------------------------------------------------------
// K1: prep (unchanged, proven). blocks 0..31: W -> WT bf16 via LDS transpose.
//     blocks 32..543: prob = softmax(target @ W_prob + b_prob).
// ---------------------------------------------------------------------------
__global__ __launch_bounds__(256) void prep_kernel(
    const float* __restrict__ tgt,
    const float* __restrict__ Wsrc, const float* __restrict__ Wtgt,
    const float* __restrict__ Wp, const float* __restrict__ bp,
    unsigned short* __restrict__ wtb, float* __restrict__ out)
{
    __shared__ float tl[64 * 65];
    const int blk = blockIdx.x, tid = threadIdx.x;

    if (blk < 32) {
        int wb = blk;
        int e = wb >> 4, ti = wb & 15, tr = ti >> 2, tc = ti & 3;
        int r0 = tr * 64, c0 = tc * 64;
        const float* W = e ? Wtgt : Wsrc;
        #pragma unroll
        for (int it = 0; it < 4; it++) {
            int rr = (tid >> 4) + it * 16;
            int cc = (tid & 15) * 4;
            float4 v = *(const float4*)&W[(r0 + rr) * D_ + c0 + cc];
            tl[(cc + 0) * 65 + rr] = v.x;
            tl[(cc + 1) * 65 + rr] = v.y;
            tl[(cc + 2) * 65 + rr] = v.z;
            tl[(cc + 3) * 65 + rr] = v.w;
        }
        __syncthreads();
        #pragma unroll
        for (int it = 0; it < 2; it++) {
            int jj = (tid >> 3) + it * 32;
            int kk = (tid & 7) * 8;
            ushort4 lo, hi;
            lo.x = f2bf(tl[jj * 65 + kk + 0]); lo.y = f2bf(tl[jj * 65 + kk + 1]);
            lo.z = f2bf(tl[jj * 65 + kk + 2]); lo.w = f2bf(tl[jj * 65 + kk + 3]);
            hi.x = f2bf(tl[jj * 65 + kk + 4]); hi.y = f2bf(tl[jj * 65 + kk + 5]);
            hi.z = f2bf(tl[jj * 65 + kk + 6]); hi.w = f2bf(tl[jj * 65 + kk + 7]);
            int idx = (e * 256 + c0 + jj) * D_ + r0 + kk;
            *(ushort4*)&wtb[idx] = lo;
            *(ushort4*)&wtb[idx + 4] = hi;
        }
    } else {
        int row  = (blk - 32) * 4 + (tid >> 6);
        int lane = tid & 63;
        float p0 = 0.f, p1 = 0.f;
        #pragma unroll
        for (int i = 0; i < 4; i++) {
            int d = lane + i * 64;
            float v = tgt[row * D_ + d];
            float2 w = *(const float2*)&Wp[d * 2];
            p0 = fmaf(v, w.x, p0);
            p1 = fmaf(v, w.y, p1);
        }
        #pragma unroll
        for (int off = 32; off > 0; off >>= 1) {
            p0 += __shfl_down(p0, off, 64);
            p1 += __shfl_down(p1, off, 64);
        }
        if (lane == 0) {
            const float L2E = 1.4426950408889634f;
            float l0 = p0 + bp[0], l1 = p1 + bp[1];
            float e10 = __builtin_amdgcn_exp2f((l1 - l0) * L2E);
            float e01 = __builtin_amdgcn_exp2f((l0 - l1) * L2E);
            out[B_ * T_ * S_ + row * 2 + 0] = __builtin_amdgcn_rcpf(1.f + e10);
            out[B_ * T_ * S_ + row * 2 + 1] = __builtin_amdgcn_rcpf(1.f + e01);
        }
    }
}

// ---------------------------------------------------------------------------
// K2: ysyt — GEMM-shaped: YS = exp(2*(src@Wsrc+b)), YT likewise, written
// TRANSPOSED: yst[d][global_row], f32 (4 MB). Transposed store is free here:
// the MFMA D-layout (col=lane&15, row=quad*4+j) gives each lane 4 consecutive
// global rows at fixed d-col -> contiguous float4 store.
// grid 256 = 64 rowblocks (64 rows) x 4 col-quarters (4 colgroups of 16).
// Producer fragments identical to the proven v12 code.
// ---------------------------------------------------------------------------
__global__ __launch_bounds__(256) void ysyt_kernel(
    const float* __restrict__ src, const float* __restrict__ tgt,
    const unsigned short* __restrict__ wtb,
    const float* __restrict__ bsrc, const float* __restrict__ btgt,
    float* __restrict__ yst)
{
    const int bx = blockIdx.x;
    const int rowblk = bx >> 2, colq = bx & 3;
    const int R0 = rowblk * 64;
    const int tid = threadIdx.x, lane = tid & 63, w = tid >> 6;
    const int n = lane & 15, quad = lane >> 4;
    const int mat = (R0 >= NSRC) ? 1 : 0;
    const float* bias = mat ? btgt : bsrc;
    const unsigned short* wtbase = wtb + mat * 256 * D_;
    const float* xb = mat ? &tgt[(R0 - NSRC) * D_] : &src[R0 * D_];

    short8 af[8];
    #pragma unroll
    for (int ks = 0; ks < 8; ks++) {
        const float* p = &xb[(w * 16 + n) * D_ + ks * 32 + quad * 8];
        float4 u0 = *(const float4*)p;
        float4 u1 = *(const float4*)(p + 4);
        short8 v;
        v[0] = (short)f2bf(u0.x); v[1] = (short)f2bf(u0.y);
        v[2] = (short)f2bf(u0.z); v[3] = (short)f2bf(u0.w);
        v[4] = (short)f2bf(u1.x); v[5] = (short)f2bf(u1.y);
        v[6] = (short)f2bf(u1.z); v[7] = (short)f2bf(u1.w);
        af[ks] = v;
    }

    #pragma unroll
    for (int gc = 0; gc < 4; gc++) {
        const int gcol = colq * 4 + gc;
        const unsigned short* bptr = &wtbase[(gcol * 16 + n) * D_ + quad * 8];
        short8 bf[8];
        #pragma unroll
        for (int ks = 0; ks < 8; ks++) bf[ks] = *(const short8*)&bptr[ks * 32];
        f32x4 a4 = {0.f, 0.f, 0.f, 0.f};
        #pragma unroll
        for (int ks = 0; ks < 8; ks++)
            a4 = __builtin_amdgcn_mfma_f32_16x16x32_bf16(af[ks], bf[ks], a4, 0, 0, 0);
        const float bv = bias[gcol * 16 + n];
        float4 o;
        o.x = __builtin_amdgcn_exp2f((a4[0] + bv) * K2F);
        o.y = __builtin_amdgcn_exp2f((a4[1] + bv) * K2F);
        o.z = __builtin_amdgcn_exp2f((a4[2] + bv) * K2F);
        o.w = __builtin_amdgcn_exp2f((a4[3] + bv) * K2F);
        *(float4*)&yst[(gcol * 16 + n) * NROW + R0 + w * 16 + quad * 4] = o;
    }
}

// ---------------------------------------------------------------------------
// K3: genp — homogeneous consumer. Tile 32s x 32t, grid (16,16,4) = 1024
// blocks, 256 thr (4 waves), 4 blocks/CU (LDS 37KB, natural VGPR alloc).
// d-chunks of 64, double-buffered; staging = coalesced float4 from yst +
// ds_write_b128 (yst pre-transposed, no LDS transpose needed). Each thread:
// 2s x 2t, 8-term rcp folding (proven math).
// LDS row stride 36 floats: consumer reads are bank-conflict-free
// (words 4d+2m / 4d+2g cover 32 banks once, 4-lane broadcast).
// genP = C0 - 2 * sum_d w_d / (1 + ys*yt),  C0 = sum w + b_res.
// ---------------------------------------------------------------------------
#define CLS 36
__global__ __launch_bounds__(256) void genp_kernel(
    const float* __restrict__ yst,
    const float* __restrict__ Wres, const float* __restrict__ bres,
    float* __restrict__ out)
{
    __shared__ float lys[2][64][CLS];
    __shared__ float lyt[2][64][CLS];
    __shared__ float c0s;

    const int tid = threadIdx.x;
    const int lane = tid & 63, w = tid >> 6;
    const int s0 = blockIdx.x * 32;
    const int t0 = blockIdx.y * 32;
    const int b  = blockIdx.z;
    const int m = tid & 15;            // s-pair: s0 + 2m, 2m+1
    const int g = tid >> 4;            // t-pair: t0 + 2g, 2g+1
    const int r = tid >> 3;            // staging row 0..31
    const int q = tid & 7;             // staging quad 0..7

    if (w == 0) {
        float s = Wres[lane] + Wres[lane + 64] + Wres[lane + 128] + Wres[lane + 192];
        #pragma unroll
        for (int off = 32; off > 0; off >>= 1) s += __shfl_xor(s, off, 64);
        if (lane == 0) c0s = s + bres[0];
    }

    const int ysbase = b * S_ + s0;
    const int ytbase = NSRC + b * T_ + t0;

    // stage chunk 0 into buffer 0
    {
        float4 a0 = *(const float4*)&yst[(r)      * NROW + ysbase + 4 * q];
        float4 a1 = *(const float4*)&yst[(r + 32) * NROW + ysbase + 4 * q];
        float4 b0 = *(const float4*)&yst[(r)      * NROW + ytbase + 4 * q];
        float4 b1 = *(const float4*)&yst[(r + 32) * NROW + ytbase + 4 * q];
        *(float4*)&lys[0][r][4 * q]      = a0;
        *(float4*)&lys[0][r + 32][4 * q] = a1;
        *(float4*)&lyt[0][r][4 * q]      = b0;
        *(float4*)&lyt[0][r + 32][4 * q] = b1;
    }
    __syncthreads();

    f32x2 acc[2];
    acc[0] = (f32x2){0.f, 0.f};
    acc[1] = (f32x2){0.f, 0.f};
    const f32x2 one2 = {1.f, 1.f};

    for (int c = 0; c < 4; c++) {
        const int bi = c & 1;
        // issue next-chunk global loads early (latency hides under consume)
        float4 pa0, pa1, pb0, pb1;
        if (c < 3) {
            const int dn = (c + 1) * 64;
            pa0 = *(const float4*)&yst[(dn + r)      * NROW + ysbase + 4 * q];
            pa1 = *(const float4*)&yst[(dn + r + 32) * NROW + ysbase + 4 * q];
            pb0 = *(const float4*)&yst[(dn + r)      * NROW + ytbase + 4 * q];
            pb1 = *(const float4*)&yst[(dn + r + 32) * NROW + ytbase + 4 * q];
        }

        const float* wp = &Wres[c * 64];
        #pragma unroll 2
        for (int kq = 0; kq < 8; kq++) {
            const int d0 = 8 * kq;
            f32x2 ap[8];
            float2 ct[8];
            f32x2 wv[8];
            #pragma unroll
            for (int k = 0; k < 8; k++) {
                float2 a2 = *(const float2*)&lys[bi][d0 + k][2 * m];
                ct[k] = *(const float2*)&lyt[bi][d0 + k][2 * g];
                ap[k] = (f32x2){a2.x, a2.y};
                const float wk = wp[d0 + k];     // uniform s_load
                wv[k] = (f32x2){wk, wk};
            }
            #pragma unroll
            for (int i = 0; i < 2; i++) {
                const float c0 = i ? ct[0].y : ct[0].x;
                f32x2 dd[8];
                #pragma unroll
                for (int k = 0; k < 8; k++) {
                    const float cv = i ? ct[k].y : ct[k].x;
                    const f32x2 cs = {cv, cv};
                    dd[k] = ap[k] * cs + one2;   // 1 + ys*yt
                }
                f32x2 p01 = dd[0] * dd[1];
                f32x2 p23 = dd[2] * dd[3];
                f32x2 p45 = dd[4] * dd[5];
                f32x2 p67 = dd[6] * dd[7];
                f32x2 q03 = p01 * p23;
                f32x2 q47 = p45 * p67;
                f32x2 den = q03 * q47;
                f32x2 u01 = dd[1] * wv[0]; u01 = dd[0] * wv[1] + u01;
                f32x2 u23 = dd[3] * wv[2]; u23 = dd[2] * wv[3] + u23;
                f32x2 u45 = dd[5] * wv[4]; u45 = dd[4] * wv[5] + u45;
                f32x2 u67 = dd[7] * wv[6]; u67 = dd[6] * wv[7] + u67;
                f32x2 n03 = u01 * p23; n03 = u23 * p01 + n03;
                f32x2 n47 = u45 * p67; n47 = u67 * p45 + n47;
                f32x2 num = n03 * q47; num = n47 * q03 + num;
                f32x2 rr;
                rr.x = __builtin_amdgcn_rcpf(den.x);
                rr.y = __builtin_amdgcn_rcpf(den.y);
                acc[i] = num * rr + acc[i];
                (void)c0;
            }
        }

        if (c < 3) {
            *(float4*)&lys[bi ^ 1][r][4 * q]      = pa0;
            *(float4*)&lys[bi ^ 1][r + 32][4 * q] = pa1;
            *(float4*)&lyt[bi ^ 1][r][4 * q]      = pb0;
            *(float4*)&lyt[bi ^ 1][r + 32][4 * q] = pb1;
        }
        __syncthreads();
    }

    const float C0 = c0s;
    #pragma unroll
    for (int i = 0; i < 2; i++) {
        float2 o;
        o.x = C0 - 2.f * acc[i].x;
        o.y = C0 - 2.f * acc[i].y;
        *(float2*)&out[(b * T_ + t0 + 2 * g + i) * S_ + s0 + 2 * m] = o;
    }
}

extern "C" void kernel_launch(void* const* d_in, const int* in_sizes, int n_in,
                              void* d_out, int out_size, void* d_ws, size_t ws_size,
                              hipStream_t stream) {
    const float* source = (const float*)d_in[0];
    const float* target = (const float*)d_in[1];
    const float* W_src  = (const float*)d_in[2];
    const float* b_src  = (const float*)d_in[3];
    const float* W_tgt  = (const float*)d_in[4];
    const float* b_tgt  = (const float*)d_in[5];
    const float* W_res  = (const float*)d_in[6];
    const float* b_res  = (const float*)d_in[7];
    const float* W_prob = (const float*)d_in[8];
    const float* b_prob = (const float*)d_in[9];
    float* out = (float*)d_out;

    unsigned short* wtb = (unsigned short*)d_ws;          // 2*256*256 bf16 = 256 KB
    float* yst = (float*)((char*)d_ws + 256 * 1024);      // [256][4096] f32 = 4 MB

    prep_kernel<<<544, 256, 0, stream>>>(target, W_src, W_tgt,
                                         W_prob, b_prob, wtb, out);
    ysyt_kernel<<<256, 256, 0, stream>>>(source, target, wtb,
                                         b_src, b_tgt, yst);
    genp_kernel<<<dim3(16, 16, 4), 256, 0, stream>>>(yst, W_res, b_res, out);
}